// Round 1
// baseline (27264.621 us; speedup 1.0000x reference)
//
#include <hip/hip_runtime.h>
#include <hip/hip_cooperative_groups.h>

namespace cg = cooperative_groups;

typedef unsigned short u16;
typedef unsigned int   u32;
typedef _Float16 f16;
typedef f16   f16x2 __attribute__((ext_vector_type(2)));
typedef f16   f16x8 __attribute__((ext_vector_type(8)));
typedef float f32x4 __attribute__((ext_vector_type(4)));
typedef u32   u32x4 __attribute__((ext_vector_type(4)));

#define B_  64
#define L_  384
#define CS  512   // SRC_DIM
#define H_  512
#define E_  256
#define NC  250
#define T_  127
#define XROW 1024  // per-batch X row: [ctx(512) | h(512)] f16

__device__ __forceinline__ float h2f(u16 u){ f16 h; __builtin_memcpy(&h,&u,2); return (float)h; }
__device__ __forceinline__ u16  f2h(float f){ f16 h=(f16)f; u16 u; __builtin_memcpy(&u,&h,2); return u; }
__device__ __forceinline__ float wredsum(float v){
#pragma unroll
  for (int o=32;o>0;o>>=1) v += __shfl_down(v, o, 64);
  return v;
}
__device__ __forceinline__ float tanh_f(float x){
  x = fminf(fmaxf(x, -15.f), 15.f);
  float e = __expf(2.f*x);
  return (e-1.f)/(e+1.f);
}
__device__ __forceinline__ float sigm_f(float x){
  x = fminf(fmaxf(x, -30.f), 30.f);
  return 1.f/(1.f+__expf(-x));
}
__device__ __forceinline__ float dot2f(u32 a, u32 b, float c){
  f16x2 x, y; __builtin_memcpy(&x,&a,4); __builtin_memcpy(&y,&b,4);
#if __has_builtin(__builtin_amdgcn_fdot2)
  return __builtin_amdgcn_fdot2(x, y, c, false);
#else
  return c + (float)x[0]*(float)y[0] + (float)x[1]*(float)y[1];
#endif
}

// ---------------- one-time converters ----------------
__global__ __launch_bounds__(256) void k_cvt(const float* __restrict__ in, f16* __restrict__ o, int n){
  int i = blockIdx.x*256 + threadIdx.x;
  if (i < n) o[i] = (f16)in[i];
}

// Permuted gates-weight pack. Packed row p = j*16 + g*4 + hl  <->  orig row r = g*512 + j*4 + hl.
// cols: [0,768) = W_ih row r, [768,1280) = W_hh row r. Also bias_g[p] = b_ih[r]+b_hh[r].
__global__ __launch_bounds__(256) void k_packwg(const float* __restrict__ Wih,
    const float* __restrict__ Whh, const float* __restrict__ bih, const float* __restrict__ bhh,
    f16* __restrict__ Wg, float* __restrict__ bias_g){
  int i = blockIdx.x*256 + threadIdx.x;   // over 2048*1280
  if (i < 2048*1280){
    int p = i / 1280, c = i - p*1280;
    int j = p >> 4, q = p & 15, g = q >> 2, hl = q & 3;
    int r = g*512 + (j<<2) + hl;
    float v = (c < 768) ? Wih[(size_t)r*768 + c] : Whh[(size_t)r*512 + (c-768)];
    Wg[i] = (f16)v;
    if (c == 0) bias_g[p] = bih[r] + bhh[r];
  }
}

// Precompute all step embeddings: embseq[(b*T + t)*256 + col] (f16)
__global__ __launch_bounds__(256) void k_emb(const int* __restrict__ text,
    const float* __restrict__ embt, f16* __restrict__ embseq){
  int i = blockIdx.x*256 + threadIdx.x;
  if (i < B_*T_*E_){
    int bt = i >> 8, col = i & 255;
    int tok = text[bt];
    embseq[i] = (f16)embt[(size_t)tok*E_ + col];
  }
}

// ---------------- GEMM1 (MFMA): sf = src(f32) @ Wi2h16^T -> f16. M=24576, N=512, K=512
// grid (384, 2) x 256 thr. Block: 64 m-rows x 256 n-cols; wave w owns 64 n-cols.
__global__ __launch_bounds__(256) void k_sf_mfma(
    const float* __restrict__ A, const f16* __restrict__ Wn, u16* __restrict__ sf)
{
  int w = threadIdx.x >> 6, lane = threadIdx.x & 63;
  int quad = lane >> 4, l16 = lane & 15;
  int m0 = blockIdx.x * 64;
  int nb = blockIdx.y * 256 + w * 64;
  const float* ap0 = A  + (size_t)(m0 + l16)*512 + quad*8;
  const f16*   bp0 = Wn + (size_t)(nb + l16)*512 + quad*8;
  f32x4 acc[4][4] = {};   // [f(m-tile)][nt(n-tile)]
  for (int k0=0; k0<512; k0+=32){
    f16x8 bfr[4];
#pragma unroll
    for (int nt=0; nt<4; nt++)
      bfr[nt] = *(const f16x8*)(bp0 + (size_t)nt*16*512 + k0);
#pragma unroll
    for (int f=0; f<4; f++){
      const float* ap = ap0 + (size_t)f*16*512 + k0;
      float4 a0 = *(const float4*)ap;
      float4 a1 = *(const float4*)(ap+4);
      f16x8 afr = { (f16)a0.x,(f16)a0.y,(f16)a0.z,(f16)a0.w,
                    (f16)a1.x,(f16)a1.y,(f16)a1.z,(f16)a1.w };
#pragma unroll
      for (int nt=0; nt<4; nt++)
        acc[f][nt] = __builtin_amdgcn_mfma_f32_16x16x32_f16(afr, bfr[nt], acc[f][nt], 0,0,0);
    }
  }
#pragma unroll
  for (int f=0; f<4; f++)
#pragma unroll
    for (int nt=0; nt<4; nt++)
#pragma unroll
      for (int r=0; r<4; r++){
        int m = m0 + f*16 + quad*4 + r;
        int n = nb + nt*16 + l16;
        sf[(size_t)m*512 + n] = f2h(acc[f][nt][r]);
      }
}

// ---------------- GEMM2: probs = hs @ Wgen^T + bgen (A f16, W f32, out f32) -- unchanged
__global__ __launch_bounds__(256) void gemm_probs(
    const u16* __restrict__ A, const float* __restrict__ W, const float* __restrict__ bias,
    float* __restrict__ Cd, int M, int N, int K)
{
  __shared__ float As[16][64+1];
  __shared__ float Ws[16][64+1];
  const int tid = threadIdx.x;
  const int bm = blockIdx.x*64, bn = blockIdx.y*64;
  const int lr = tid>>2;
  const int lc = (tid&3)*4;
  const int ty = tid>>4, tx = tid&15;
  float acc[4][4];
#pragma unroll
  for (int i=0;i<4;i++)
#pragma unroll
    for (int j=0;j<4;j++) acc[i][j]=0.f;

  for (int k0=0;k0<K;k0+=16){
    ushort4 va = *(const ushort4*)(A + (size_t)(bm+lr)*K + k0 + lc);
    As[lc+0][lr]=h2f(va.x); As[lc+1][lr]=h2f(va.y); As[lc+2][lr]=h2f(va.z); As[lc+3][lr]=h2f(va.w);
    int n = bn + lr;
    if (n < N){
      float4 vw = *(const float4*)(W + (size_t)n*K + k0 + lc);
      Ws[lc+0][lr]=vw.x; Ws[lc+1][lr]=vw.y; Ws[lc+2][lr]=vw.z; Ws[lc+3][lr]=vw.w;
    } else {
      Ws[lc+0][lr]=0.f; Ws[lc+1][lr]=0.f; Ws[lc+2][lr]=0.f; Ws[lc+3][lr]=0.f;
    }
    __syncthreads();
#pragma unroll
    for (int k=0;k<16;k++){
      float a[4], w[4];
#pragma unroll
      for (int i=0;i<4;i++) a[i]=As[k][ty*4+i];
#pragma unroll
      for (int j=0;j<4;j++) w[j]=Ws[k][tx*4+j];
#pragma unroll
      for (int i=0;i<4;i++)
#pragma unroll
        for (int j=0;j<4;j++) acc[i][j] += a[i]*w[j];
    }
    __syncthreads();
  }
#pragma unroll
  for (int i=0;i<4;i++){
    int m = bm + ty*4 + i;
#pragma unroll
    for (int j=0;j<4;j++){
      int n = bn + tx*4 + j;
      if (n < N) Cd[(size_t)m*N + n] = acc[i][j] + bias[n];
    }
  }
}

// ---------------- persistent cooperative kernel: all 127 decode steps ----------------
// grid = 256 blocks x 256 threads. 3 grid syncs / step.
// Phase A: block g -> (b=g>>2, p=g&3): proj[b] (redundant x4, fdot2) + logit l-slice of 96.
// Phase B: block g -> (b, c-slice of 128): softmax over L (redundant x4) + context slice.
// Phase C: blocks 0..127: block j owns h-dims [4j,4j+4) x 4 gates (16 packed rows), MFMA + cell.
__global__ __launch_bounds__(256) void k_loop(
    const f16* __restrict__ sf, const float* __restrict__ src,
    const f16* __restrict__ WhF, const float* __restrict__ bh2h,
    const float* __restrict__ wsc,
    const f16* __restrict__ WgF, const float* __restrict__ bias_g,
    const f16* __restrict__ embseq,
    f16* __restrict__ X0, f16* __restrict__ X1,
    float* __restrict__ logitws, float* __restrict__ cbuf,
    u16* __restrict__ hs)
{
  cg::grid_group grid = cg::this_grid();
  const int tid  = threadIdx.x;
  const int gid  = blockIdx.x;
  const int wid  = tid >> 6;
  const int lane = tid & 63;

  __shared__ float sh_w[512];
  __shared__ float sh_bh[512];
  __shared__ float sh_proj[512];
  __shared__ u32   sh_h[256];      // h as f16x2 pairs
  __shared__ float sh_al[L_];
  __shared__ float sh_red[8];
  __shared__ float sh_tmp[256];
  __shared__ float gbuf[64][17];

  sh_w[tid]  = wsc[tid];   sh_w[256+tid]  = wsc[256+tid];
  sh_bh[tid] = bh2h[tid];  sh_bh[256+tid] = bh2h[256+tid];
  __syncthreads();

  const int bA = gid >> 2, pA = gid & 3;

  for (int t=0; t<T_; ++t){
    f16* Xc = (t & 1) ? X1 : X0;
    f16* Xn = (t & 1) ? X0 : X1;

    // ================= Phase A: proj + logit =================
    {
      const u32* hp = (const u32*)(Xc + (size_t)bA*XROW + 512);
      sh_h[tid] = hp[tid];
      __syncthreads();
      const u32x4* hh = (const u32x4*)sh_h;
#pragma unroll
      for (int nn=0; nn<2; nn++){
        int n = tid + nn*256;
        const u32x4* wr = (const u32x4*)(WhF + (size_t)n*512);
        float a0 = sh_bh[n], a1 = 0.f, a2 = 0.f, a3 = 0.f;
#pragma unroll 8
        for (int k=0;k<64;k++){
          u32x4 wq = wr[k];
          u32x4 hq = hh[k];
          a0 = dot2f(wq.x, hq.x, a0);
          a1 = dot2f(wq.y, hq.y, a1);
          a2 = dot2f(wq.z, hq.z, a2);
          a3 = dot2f(wq.w, hq.w, a3);
        }
        sh_proj[n] = (a0+a1) + (a2+a3);
      }
      __syncthreads();
      float pv[8], wvv[8];
#pragma unroll
      for (int j=0;j<8;j++){ pv[j]=sh_proj[lane*8+j]; wvv[j]=sh_w[lane*8+j]; }
      const int l0 = pA*96 + wid*24;
      const f16* sp0 = sf + (((size_t)(bA*L_ + l0))<<9) + lane*8;
#pragma unroll 4
      for (int i=0;i<24;i++){
        f16x8 s = *(const f16x8*)(sp0 + ((size_t)i<<9));
        float v;
        v  = tanh_f((float)s[0]+pv[0])*wvv[0];
        v += tanh_f((float)s[1]+pv[1])*wvv[1];
        v += tanh_f((float)s[2]+pv[2])*wvv[2];
        v += tanh_f((float)s[3]+pv[3])*wvv[3];
        v += tanh_f((float)s[4]+pv[4])*wvv[4];
        v += tanh_f((float)s[5]+pv[5])*wvv[5];
        v += tanh_f((float)s[6]+pv[6])*wvv[6];
        v += tanh_f((float)s[7]+pv[7])*wvv[7];
        v = wredsum(v);
        if (lane==0) logitws[bA*L_ + l0 + i] = v;
      }
    }
    __threadfence();
    grid.sync();

    // ================= Phase B: softmax + context slice =================
    {
      const int c0 = (gid & 3) << 7;
      float va = logitws[bA*L_ + tid];
      float vb = (tid < 128) ? logitws[bA*L_ + 256 + tid] : -3.0e38f;
      float m = fmaxf(va, vb);
#pragma unroll
      for (int o=32;o>0;o>>=1) m = fmaxf(m, __shfl_down(m,o,64));
      if (lane==0) sh_red[wid] = m;
      __syncthreads();
      m = fmaxf(fmaxf(sh_red[0],sh_red[1]), fmaxf(sh_red[2],sh_red[3]));
      float ea = __expf(va - m);
      sh_al[tid] = ea;
      float ssum = ea;
      if (tid < 128){ float eb = __expf(vb - m); sh_al[256+tid] = eb; ssum += eb; }
      ssum = wredsum(ssum);
      if (lane==0) sh_red[4+wid] = ssum;
      __syncthreads();
      float inv = 1.f/((sh_red[4]+sh_red[5])+(sh_red[6]+sh_red[7]));
      int c = c0 + (tid & 127);
      int half = tid >> 7;
      const float* sp = src + ((size_t)(bA*L_ + half*192))*512 + c;
      float acc = 0.f;
#pragma unroll 16
      for (int l=0;l<192;l++) acc += sh_al[half*192+l]*sp[(size_t)l<<9];
      sh_tmp[tid] = acc;
      __syncthreads();
      if (tid < 128)
        Xc[(size_t)bA*XROW + c0 + tid] = (f16)((sh_tmp[tid]+sh_tmp[128+tid])*inv);
    }
    __threadfence();
    grid.sync();

    // ================= Phase C: gates MFMA + LSTM cell =================
    if (gid < 128){
      const int j = gid;
      const int quad = lane >> 4, l16 = lane & 15;
      const f16* bp   = WgF + (size_t)(j*16 + l16)*1280 + quad*8;
      const int brow  = wid*16 + l16;
      const f16* actx = Xc + (size_t)brow*XROW + quad*8;
      const f16* aemb = embseq + (((size_t)brow*T_ + t)<<8) + quad*8;
      const f16* ah   = actx + 512;
      f32x4 acc = {};
#pragma unroll
      for (int k0=0;k0<512;k0+=32)
        acc = __builtin_amdgcn_mfma_f32_16x16x32_f16(*(const f16x8*)(actx+k0), *(const f16x8*)(bp+k0), acc, 0,0,0);
#pragma unroll
      for (int k0=0;k0<256;k0+=32)
        acc = __builtin_amdgcn_mfma_f32_16x16x32_f16(*(const f16x8*)(aemb+k0), *(const f16x8*)(bp+512+k0), acc, 0,0,0);
#pragma unroll
      for (int k0=0;k0<512;k0+=32)
        acc = __builtin_amdgcn_mfma_f32_16x16x32_f16(*(const f16x8*)(ah+k0), *(const f16x8*)(bp+768+k0), acc, 0,0,0);
#pragma unroll
      for (int r=0;r<4;r++) gbuf[wid*16 + quad*4 + r][l16] = acc[r];
      __syncthreads();
      const int b = tid >> 2, hl = tid & 3;
      const int hd = j*4 + hl;
      float gi = gbuf[b][ 0+hl] + bias_g[j*16 +  0 + hl];
      float gf = gbuf[b][ 4+hl] + bias_g[j*16 +  4 + hl];
      float gg = gbuf[b][ 8+hl] + bias_g[j*16 +  8 + hl];
      float go = gbuf[b][12+hl] + bias_g[j*16 + 12 + hl];
      float fi=sigm_f(gi), ff=sigm_f(gf), fg=tanh_f(gg), fo=sigm_f(go);
      size_t ci = ((size_t)b<<9) + hd;
      float cn = ff*cbuf[ci] + fi*fg;
      float hn = fo*tanh_f(cn);
      cbuf[ci] = cn;
      Xn[(size_t)b*XROW + 512 + hd] = (f16)hn;
      hs[(((size_t)(b*T_ + t))<<9) + hd] = f2h(hn);
    }
    __threadfence();
    grid.sync();
  }
}

extern "C" void kernel_launch(void* const* d_in, const int* in_sizes, int n_in,
                              void* d_out, int out_size, void* d_ws, size_t ws_size,
                              hipStream_t stream)
{
  const float* src   = (const float*)d_in[0];
  const int*   text  = (const int*)d_in[1];
  const float* embt  = (const float*)d_in[2];
  const float* Wi2h  = (const float*)d_in[3];
  const float* Wh2h  = (const float*)d_in[4];
  const float* bh2h  = (const float*)d_in[5];
  const float* wsc   = (const float*)d_in[6];
  const float* W_ih  = (const float*)d_in[7];
  const float* b_ih  = (const float*)d_in[8];
  const float* W_hh  = (const float*)d_in[9];
  const float* b_hh  = (const float*)d_in[10];
  const float* Wgen  = (const float*)d_in[11];
  const float* bgen  = (const float*)d_in[12];
  float* out = (float*)d_out;

  // Workspace layout (~44.3 MB)
  char* p = (char*)d_ws;
  u16*   sfw    = (u16*)p;    p += (size_t)B_*L_*H_*2;     // 25.2 MB
  u16*   hsw    = (u16*)p;    p += (size_t)B_*T_*H_*2;     //  8.3 MB
  f16*   WhF    = (f16*)p;    p += (size_t)H_*H_*2;        //  0.5 MB
  f16*   Wi2h16 = (f16*)p;    p += (size_t)H_*CS*2;        //  0.5 MB
  f16*   WgF    = (f16*)p;    p += (size_t)2048*1280*2;    //  5.2 MB
  f16*   embseq = (f16*)p;    p += (size_t)B_*T_*E_*2;     //  4.2 MB
  f16*   X0     = (f16*)p;    p += (size_t)B_*XROW*2;      //  128 KB
  f16*   X1     = (f16*)p;    p += (size_t)B_*XROW*2;      //  128 KB
  float* logitw = (float*)p;  p += (size_t)B_*L_*4;        //   98 KB
  float* cbuf   = (float*)p;  p += (size_t)B_*H_*4;        //  128 KB
  float* bias_g = (float*)p;  p += (size_t)2048*4;         //    8 KB

  hipMemsetAsync(X0,   0, (size_t)B_*XROW*2*2, stream);    // X0 + X1 (contiguous)
  hipMemsetAsync(cbuf, 0, (size_t)B_*H_*4, stream);

  // one-time conversions / packing
  k_cvt   <<<(H_*H_+255)/256,  256, 0, stream>>>(Wh2h, WhF, H_*H_);
  k_cvt   <<<(H_*CS+255)/256,  256, 0, stream>>>(Wi2h, Wi2h16, H_*CS);
  k_packwg<<<(2048*1280+255)/256, 256, 0, stream>>>(W_ih, W_hh, b_ih, b_hh, WgF, bias_g);
  k_emb   <<<(B_*T_*E_+255)/256, 256, 0, stream>>>(text, embt, embseq);

  // sf = src @ Wi2h^T  (MFMA f16)
  k_sf_mfma<<<dim3(384,2), 256, 0, stream>>>(src, Wi2h16, sfw);

  // persistent decode loop (cooperative)
  const f16* sf_h = (const f16*)sfw;
  void* ka[] = {
    (void*)&sf_h, (void*)&src, (void*)&WhF, (void*)&bh2h, (void*)&wsc,
    (void*)&WgF, (void*)&bias_g, (void*)&embseq,
    (void*)&X0, (void*)&X1, (void*)&logitw, (void*)&cbuf, (void*)&hsw
  };
  hipLaunchCooperativeKernel(reinterpret_cast<void*>(k_loop),
                             dim3(256), dim3(256), ka, 0, stream);

  // probs = hs @ Wgen^T + bgen
  dim3 g2(B_*T_/64, (NC+63)/64);
  gemm_probs<<<g2, 256, 0, stream>>>(hsw, Wgen, bgen, out, B_*T_, NC, H_);
}

// Round 2
// 10364.281 us; speedup vs baseline: 2.6306x; 2.6306x over previous
//
#include <hip/hip_runtime.h>

typedef unsigned short u16;
typedef unsigned int   u32;
typedef _Float16 f16;
typedef f16   f16x2 __attribute__((ext_vector_type(2)));
typedef f16   f16x8 __attribute__((ext_vector_type(8)));
typedef float f32x4 __attribute__((ext_vector_type(4)));
typedef u32   u32x4 __attribute__((ext_vector_type(4)));

#define B_  64
#define L_  384
#define CS  512   // SRC_DIM
#define H_  512
#define E_  256
#define NC  250
#define T_  127
#define XROW 1024  // per-batch X row: [ctx(512) | h(512)] f16

__device__ __forceinline__ float h2f(u16 u){ f16 h; __builtin_memcpy(&h,&u,2); return (float)h; }
__device__ __forceinline__ u16  f2h(float f){ f16 h=(f16)f; u16 u; __builtin_memcpy(&u,&h,2); return u; }
__device__ __forceinline__ float wredsum(float v){
#pragma unroll
  for (int o=32;o>0;o>>=1) v += __shfl_down(v, o, 64);
  return v;
}
__device__ __forceinline__ float tanh_f(float x){
  x = fminf(fmaxf(x, -15.f), 15.f);
  float e = __expf(2.f*x);
  return (e-1.f)/(e+1.f);
}
__device__ __forceinline__ float sigm_f(float x){
  x = fminf(fmaxf(x, -30.f), 30.f);
  return 1.f/(1.f+__expf(-x));
}
__device__ __forceinline__ float dot2f(u32 a, u32 b, float c){
  f16x2 x, y; __builtin_memcpy(&x,&a,4); __builtin_memcpy(&y,&b,4);
#if __has_builtin(__builtin_amdgcn_fdot2)
  return __builtin_amdgcn_fdot2(x, y, c, false);
#else
  return c + (float)x[0]*(float)y[0] + (float)x[1]*(float)y[1];
#endif
}

// ---------------- one-time converters ----------------
__global__ __launch_bounds__(256) void k_cvt(const float* __restrict__ in, f16* __restrict__ o, int n){
  int i = blockIdx.x*256 + threadIdx.x;
  if (i < n) o[i] = (f16)in[i];
}

// Permuted gates-weight pack. Packed row p = j*16 + g*4 + hl  <->  orig row r = g*512 + j*4 + hl.
// cols: [0,768) = W_ih row r, [768,1280) = W_hh row r. Also bias_g[p] = b_ih[r]+b_hh[r].
__global__ __launch_bounds__(256) void k_packwg(const float* __restrict__ Wih,
    const float* __restrict__ Whh, const float* __restrict__ bih, const float* __restrict__ bhh,
    f16* __restrict__ Wg, float* __restrict__ bias_g){
  int i = blockIdx.x*256 + threadIdx.x;   // over 2048*1280
  if (i < 2048*1280){
    int p = i / 1280, c = i - p*1280;
    int j = p >> 4, q = p & 15, g = q >> 2, hl = q & 3;
    int r = g*512 + (j<<2) + hl;
    float v = (c < 768) ? Wih[(size_t)r*768 + c] : Whh[(size_t)r*512 + (c-768)];
    Wg[i] = (f16)v;
    if (c == 0) bias_g[p] = bih[r] + bhh[r];
  }
}

// Precompute all step embeddings: embseq[(b*T + t)*256 + col] (f16)
__global__ __launch_bounds__(256) void k_emb(const int* __restrict__ text,
    const float* __restrict__ embt, f16* __restrict__ embseq){
  int i = blockIdx.x*256 + threadIdx.x;
  if (i < B_*T_*E_){
    int bt = i >> 8, col = i & 255;
    int tok = text[bt];
    embseq[i] = (f16)embt[(size_t)tok*E_ + col];
  }
}

// ---------------- GEMM1 (MFMA): sf = src(f32) @ Wi2h16^T -> f16. M=24576, N=512, K=512
__global__ __launch_bounds__(256) void k_sf_mfma(
    const float* __restrict__ A, const f16* __restrict__ Wn, u16* __restrict__ sf)
{
  int w = threadIdx.x >> 6, lane = threadIdx.x & 63;
  int quad = lane >> 4, l16 = lane & 15;
  int m0 = blockIdx.x * 64;
  int nb = blockIdx.y * 256 + w * 64;
  const float* ap0 = A  + (size_t)(m0 + l16)*512 + quad*8;
  const f16*   bp0 = Wn + (size_t)(nb + l16)*512 + quad*8;
  f32x4 acc[4][4] = {};   // [f(m-tile)][nt(n-tile)]
  for (int k0=0; k0<512; k0+=32){
    f16x8 bfr[4];
#pragma unroll
    for (int nt=0; nt<4; nt++)
      bfr[nt] = *(const f16x8*)(bp0 + (size_t)nt*16*512 + k0);
#pragma unroll
    for (int f=0; f<4; f++){
      const float* ap = ap0 + (size_t)f*16*512 + k0;
      float4 a0 = *(const float4*)ap;
      float4 a1 = *(const float4*)(ap+4);
      f16x8 afr = { (f16)a0.x,(f16)a0.y,(f16)a0.z,(f16)a0.w,
                    (f16)a1.x,(f16)a1.y,(f16)a1.z,(f16)a1.w };
#pragma unroll
      for (int nt=0; nt<4; nt++)
        acc[f][nt] = __builtin_amdgcn_mfma_f32_16x16x32_f16(afr, bfr[nt], acc[f][nt], 0,0,0);
    }
  }
#pragma unroll
  for (int f=0; f<4; f++)
#pragma unroll
    for (int nt=0; nt<4; nt++)
#pragma unroll
      for (int r=0; r<4; r++){
        int m = m0 + f*16 + quad*4 + r;
        int n = nb + nt*16 + l16;
        sf[(size_t)m*512 + n] = f2h(acc[f][nt][r]);
      }
}

// ---------------- GEMM2: probs = hs @ Wgen^T + bgen (A f16, W f32, out f32)
__global__ __launch_bounds__(256) void gemm_probs(
    const u16* __restrict__ A, const float* __restrict__ W, const float* __restrict__ bias,
    float* __restrict__ Cd, int M, int N, int K)
{
  __shared__ float As[16][64+1];
  __shared__ float Ws[16][64+1];
  const int tid = threadIdx.x;
  const int bm = blockIdx.x*64, bn = blockIdx.y*64;
  const int lr = tid>>2;
  const int lc = (tid&3)*4;
  const int ty = tid>>4, tx = tid&15;
  float acc[4][4];
#pragma unroll
  for (int i=0;i<4;i++)
#pragma unroll
    for (int j=0;j<4;j++) acc[i][j]=0.f;

  for (int k0=0;k0<K;k0+=16){
    ushort4 va = *(const ushort4*)(A + (size_t)(bm+lr)*K + k0 + lc);
    As[lc+0][lr]=h2f(va.x); As[lc+1][lr]=h2f(va.y); As[lc+2][lr]=h2f(va.z); As[lc+3][lr]=h2f(va.w);
    int n = bn + lr;
    if (n < N){
      float4 vw = *(const float4*)(W + (size_t)n*K + k0 + lc);
      Ws[lc+0][lr]=vw.x; Ws[lc+1][lr]=vw.y; Ws[lc+2][lr]=vw.z; Ws[lc+3][lr]=vw.w;
    } else {
      Ws[lc+0][lr]=0.f; Ws[lc+1][lr]=0.f; Ws[lc+2][lr]=0.f; Ws[lc+3][lr]=0.f;
    }
    __syncthreads();
#pragma unroll
    for (int k=0;k<16;k++){
      float a[4], w[4];
#pragma unroll
      for (int i=0;i<4;i++) a[i]=As[k][ty*4+i];
#pragma unroll
      for (int j=0;j<4;j++) w[j]=Ws[k][tx*4+j];
#pragma unroll
      for (int i=0;i<4;i++)
#pragma unroll
        for (int j=0;j<4;j++) acc[i][j] += a[i]*w[j];
    }
    __syncthreads();
  }
#pragma unroll
  for (int i=0;i<4;i++){
    int m = bm + ty*4 + i;
#pragma unroll
    for (int j=0;j<4;j++){
      int n = bn + tx*4 + j;
      if (n < N) Cd[(size_t)m*N + n] = acc[i][j] + bias[n];
    }
  }
}

// ---------------- per-step kernel 1: proj + logit + softmax + context.
// grid 64 (one block per batch) x 512 threads (8 waves).
__global__ __launch_bounds__(512) void k_att(
    const f16* __restrict__ sf, const f16* __restrict__ src16,
    const f16* __restrict__ WhF, const float* __restrict__ bh2h,
    const float* __restrict__ wsc, f16* __restrict__ Xc)
{
  const int b    = blockIdx.x;
  const int tid  = threadIdx.x;
  const int wid  = tid >> 6;
  const int lane = tid & 63;

  __shared__ __align__(16) u32 sh_h[256];   // h (512 f16)
  __shared__ float sh_proj[512];
  __shared__ float sh_logit[384];
  __shared__ float sh_al[384];
  __shared__ float sh_red[16];
  __shared__ float sh_cx[2][512];

  // ---- load h_b to LDS ----
  if (tid < 256) sh_h[tid] = ((const u32*)(Xc + (size_t)b*XROW + 512))[tid];
  __syncthreads();

  // ---- proj = h @ Wh2h^T + bh2h. 4 threads per row (k-quarters), 4 passes. ----
  {
    const int r4 = tid >> 2;      // 0..127 row-within-pass
    const int kq = tid & 3;       // k-quarter
    const u32x4* hh = (const u32x4*)sh_h + kq*16;
#pragma unroll
    for (int pass=0; pass<4; pass++){
      int n = pass*128 + r4;
      const u32x4* wr = (const u32x4*)(WhF + (size_t)n*512) + kq*16;
      float a0=0.f,a1=0.f,a2=0.f,a3=0.f;
#pragma unroll
      for (int k=0;k<16;k++){
        u32x4 wq = wr[k];
        u32x4 hq = hh[k];
        a0 = dot2f(wq.x, hq.x, a0);
        a1 = dot2f(wq.y, hq.y, a1);
        a2 = dot2f(wq.z, hq.z, a2);
        a3 = dot2f(wq.w, hq.w, a3);
      }
      float s = (a0+a1)+(a2+a3);
      s += __shfl_down(s, 1, 64);
      s += __shfl_down(s, 2, 64);
      if (kq == 0) sh_proj[n] = s + bh2h[n];
    }
  }
  __syncthreads();

  // ---- logit: 8 waves x 48 rows. lane owns 8 H-cols. ----
  {
    float pv[8], wv[8];
#pragma unroll
    for (int j=0;j<8;j++){ pv[j]=sh_proj[lane*8+j]; wv[j]=wsc[lane*8+j]; }
    const f16* sp0 = sf + (((size_t)(b*L_)) << 9) + lane*8;
    const int lbase = wid*48;
#pragma unroll 4
    for (int i=0;i<48;i++){
      int l = lbase + i;
      f16x8 s = *(const f16x8*)(sp0 + ((size_t)l << 9));
      float v;
      v  = tanh_f((float)s[0]+pv[0])*wv[0];
      v += tanh_f((float)s[1]+pv[1])*wv[1];
      v += tanh_f((float)s[2]+pv[2])*wv[2];
      v += tanh_f((float)s[3]+pv[3])*wv[3];
      v += tanh_f((float)s[4]+pv[4])*wv[4];
      v += tanh_f((float)s[5]+pv[5])*wv[5];
      v += tanh_f((float)s[6]+pv[6])*wv[6];
      v += tanh_f((float)s[7]+pv[7])*wv[7];
      v = wredsum(v);
      if (lane == 0) sh_logit[l] = v;
    }
  }
  __syncthreads();

  // ---- softmax over 384 ----
  float inv;
  {
    float va = (tid < 384) ? sh_logit[tid] : -3.0e38f;
    float m = va;
#pragma unroll
    for (int o=32;o>0;o>>=1) m = fmaxf(m, __shfl_down(m,o,64));
    if (lane==0) sh_red[wid] = m;
    __syncthreads();
    m = fmaxf(fmaxf(fmaxf(sh_red[0],sh_red[1]),fmaxf(sh_red[2],sh_red[3])),
              fmaxf(fmaxf(sh_red[4],sh_red[5]),fmaxf(sh_red[6],sh_red[7])));
    float e = (tid < 384) ? __expf(va - m) : 0.f;
    if (tid < 384) sh_al[tid] = e;
    float ssum = wredsum(e);
    if (lane==0) sh_red[8+wid] = ssum;
    __syncthreads();
    inv = 1.f/(((sh_red[8]+sh_red[9])+(sh_red[10]+sh_red[11]))
             + ((sh_red[12]+sh_red[13])+(sh_red[14]+sh_red[15])));
  }

  // ---- context: thread covers 2 cols (u32), l-range split in halves ----
  {
    const int c2   = tid & 255;     // u32 col-pair index
    const int half = tid >> 8;      // 0: l 0..191, 1: l 192..383
    const u32* sp = (const u32*)(src16 + (((size_t)(b*L_ + half*192)) << 9)) + c2;
    const float* alp = sh_al + half*192;
    float acc0 = 0.f, acc1 = 0.f;
#pragma unroll 8
    for (int l=0;l<192;l++){
      u32 v = sp[(size_t)l << 8];   // row stride = 256 u32
      float al = alp[l];
      f16x2 pr; __builtin_memcpy(&pr,&v,4);
      acc0 += al*(float)pr[0];
      acc1 += al*(float)pr[1];
    }
    sh_cx[half][c2*2  ] = acc0;
    sh_cx[half][c2*2+1] = acc1;
  }
  __syncthreads();
  if (tid < 256){
    float v0 = (sh_cx[0][tid*2  ] + sh_cx[1][tid*2  ]) * inv;
    float v1 = (sh_cx[0][tid*2+1] + sh_cx[1][tid*2+1]) * inv;
    u32 o = (u32)f2h(v0) | ((u32)f2h(v1) << 16);
    ((u32*)(Xc + (size_t)b*XROW))[tid] = o;
  }
}

// ---------------- per-step kernel 2: gates MFMA + LSTM cell.
// grid 128 x 256 thr; block j owns h-dims [4j,4j+4) x 4 gates (16 packed Wg rows).
__global__ __launch_bounds__(256) void k_gates(
    const f16* __restrict__ X, const f16* __restrict__ Wg,
    const float* __restrict__ bias_g, const f16* __restrict__ embseq,
    float* __restrict__ cbuf, f16* __restrict__ Xn, u16* __restrict__ hs, int t)
{
  __shared__ float gbuf[64][17];
  const int tid  = threadIdx.x;
  const int wid  = tid >> 6, lane = tid & 63;
  const int quad = lane >> 4, l16 = lane & 15;
  const int j = blockIdx.x;
  const f16* bp   = Wg + (size_t)(j*16 + l16)*1280 + quad*8;
  const int brow  = wid*16 + l16;
  const f16* actx = X + (size_t)brow*XROW + quad*8;
  const f16* aemb = embseq + (((size_t)brow*T_ + t)<<8) + quad*8;
  const f16* ah   = actx + 512;
  f32x4 acc = {};
#pragma unroll
  for (int k0=0;k0<512;k0+=32)
    acc = __builtin_amdgcn_mfma_f32_16x16x32_f16(*(const f16x8*)(actx+k0), *(const f16x8*)(bp+k0), acc, 0,0,0);
#pragma unroll
  for (int k0=0;k0<256;k0+=32)
    acc = __builtin_amdgcn_mfma_f32_16x16x32_f16(*(const f16x8*)(aemb+k0), *(const f16x8*)(bp+512+k0), acc, 0,0,0);
#pragma unroll
  for (int k0=0;k0<512;k0+=32)
    acc = __builtin_amdgcn_mfma_f32_16x16x32_f16(*(const f16x8*)(ah+k0), *(const f16x8*)(bp+768+k0), acc, 0,0,0);
#pragma unroll
  for (int r=0;r<4;r++) gbuf[wid*16 + quad*4 + r][l16] = acc[r];
  __syncthreads();
  const int b = tid >> 2, hl = tid & 3;
  const int hd = j*4 + hl;
  float gi = gbuf[b][ 0+hl] + bias_g[j*16 +  0 + hl];
  float gf = gbuf[b][ 4+hl] + bias_g[j*16 +  4 + hl];
  float gg = gbuf[b][ 8+hl] + bias_g[j*16 +  8 + hl];
  float go = gbuf[b][12+hl] + bias_g[j*16 + 12 + hl];
  float fi=sigm_f(gi), ff=sigm_f(gf), fg=tanh_f(gg), fo=sigm_f(go);
  size_t ci = ((size_t)b<<9) + hd;
  float cn = ff*cbuf[ci] + fi*fg;
  float hn = fo*tanh_f(cn);
  cbuf[ci] = cn;
  Xn[(size_t)b*XROW + 512 + hd] = (f16)hn;
  hs[(((size_t)(b*T_ + t))<<9) + hd] = f2h(hn);
}

extern "C" void kernel_launch(void* const* d_in, const int* in_sizes, int n_in,
                              void* d_out, int out_size, void* d_ws, size_t ws_size,
                              hipStream_t stream)
{
  const float* src   = (const float*)d_in[0];
  const int*   text  = (const int*)d_in[1];
  const float* embt  = (const float*)d_in[2];
  const float* Wi2h  = (const float*)d_in[3];
  const float* Wh2h  = (const float*)d_in[4];
  const float* bh2h  = (const float*)d_in[5];
  const float* wsc   = (const float*)d_in[6];
  const float* W_ih  = (const float*)d_in[7];
  const float* b_ih  = (const float*)d_in[8];
  const float* W_hh  = (const float*)d_in[9];
  const float* b_hh  = (const float*)d_in[10];
  const float* Wgen  = (const float*)d_in[11];
  const float* bgen  = (const float*)d_in[12];
  float* out = (float*)d_out;

  // Workspace layout (~70 MB)
  char* p = (char*)d_ws;
  u16*   sfw    = (u16*)p;    p += (size_t)B_*L_*H_*2;     // 25.2 MB
  u16*   hsw    = (u16*)p;    p += (size_t)B_*T_*H_*2;     //  8.3 MB
  f16*   src16  = (f16*)p;    p += (size_t)B_*L_*CS*2;     // 25.2 MB
  f16*   WhF    = (f16*)p;    p += (size_t)H_*H_*2;        //  0.5 MB
  f16*   Wi2h16 = (f16*)p;    p += (size_t)H_*CS*2;        //  0.5 MB
  f16*   WgF    = (f16*)p;    p += (size_t)2048*1280*2;    //  5.2 MB
  f16*   embseq = (f16*)p;    p += (size_t)B_*T_*E_*2;     //  4.2 MB
  f16*   X0     = (f16*)p;    p += (size_t)B_*XROW*2;      //  128 KB
  f16*   X1     = (f16*)p;    p += (size_t)B_*XROW*2;      //  128 KB
  float* cbuf   = (float*)p;  p += (size_t)B_*H_*4;        //  128 KB
  float* bias_g = (float*)p;  p += (size_t)2048*4;         //    8 KB

  hipMemsetAsync(X0,   0, (size_t)B_*XROW*2*2, stream);    // X0 + X1 (contiguous)
  hipMemsetAsync(cbuf, 0, (size_t)B_*H_*4, stream);

  // one-time conversions / packing
  k_cvt   <<<(H_*H_+255)/256,   256, 0, stream>>>(Wh2h, WhF, H_*H_);
  k_cvt   <<<(H_*CS+255)/256,   256, 0, stream>>>(Wi2h, Wi2h16, H_*CS);
  k_cvt   <<<(B_*L_*CS+255)/256,256, 0, stream>>>(src, src16, B_*L_*CS);
  k_packwg<<<(2048*1280+255)/256, 256, 0, stream>>>(W_ih, W_hh, b_ih, b_hh, WgF, bias_g);
  k_emb   <<<(B_*T_*E_+255)/256, 256, 0, stream>>>(text, embt, embseq);

  // sf = src @ Wi2h^T  (MFMA f16)
  k_sf_mfma<<<dim3(384,2), 256, 0, stream>>>(src, Wi2h16, sfw);

  // decode loop: 2 kernels per step
  for (int t=0; t<T_; t++){
    f16* Xc = (t & 1) ? X1 : X0;
    f16* Xn = (t & 1) ? X0 : X1;
    k_att  <<<64, 512, 0, stream>>>((const f16*)sfw, src16, WhF, bh2h, wsc, Xc);
    k_gates<<<128, 256, 0, stream>>>(Xc, WgF, bias_g, embseq, cbuf, Xn, hsw, t);
  }

  // probs = hs @ Wgen^T + bgen
  dim3 g2(B_*T_/64, (NC+63)/64);
  gemm_probs<<<g2, 256, 0, stream>>>(hsw, Wgen, bgen, out, B_*T_, NC, H_);
}